// Round 15
// baseline (305.793 us; speedup 1.0000x reference)
//
#include <hip/hip_runtime.h>
#include <hip/hip_bf16.h>

// Problem constants
#define NN 245      // tokens
#define NP 256      // padded tokens
#define HH 12       // heads
#define DD 64       // head dim
#define CC 768      // channels
#define NBUCKET 1698
#define MROWS (64 * NN)   // 15680

typedef __bf16 bf16x8 __attribute__((ext_vector_type(8)));
typedef float f32x4 __attribute__((ext_vector_type(4)));

#define MFMA(a, b, c) __builtin_amdgcn_mfma_f32_16x16x32_bf16(a, b, c, 0, 0, 0)

static __device__ __forceinline__ f32x4 fzero() {
    f32x4 z = {0.f, 0.f, 0.f, 0.f};
    return z;
}

static __device__ __forceinline__ bf16x8 cvt8(f32x4 lo, f32x4 hi) {
    bf16x8 r;
    #pragma unroll
    for (int i = 0; i < 4; ++i) { r[i] = (__bf16)lo[i]; r[i + 4] = (__bf16)hi[i]; }
    return r;
}

// async global->LDS, 16B per lane (wave-uniform LDS base + lane*16)
static __device__ __forceinline__ void gl_lds16(const __bf16* g, __bf16* l) {
    __builtin_amdgcn_global_load_lds(
        (const __attribute__((address_space(1))) void*)g,
        (__attribute__((address_space(3))) void*)l, 16, 0, 0);
}

// ---------------------------------------------------------------------------
// PREP (one launch, 3648 blocks of 256): 4 independent prep tasks concurrent
// + VT pad-column zeroing. (R10-green version verbatim)
__global__ __launch_bounds__(256) void prep(
    const float* __restrict__ x,     __bf16* __restrict__ xb,
    const float* __restrict__ wqkv,  __bf16* __restrict__ wb,
    const float* __restrict__ wproj, __bf16* __restrict__ wpb,
    const float* __restrict__ rpe, const int* __restrict__ relidx,
    const float* __restrict__ wl_, const float* __restrict__ bl_,
    __bf16* __restrict__ biasb, __bf16* __restrict__ VT)
{
    __shared__ float wl[144];
    __shared__ float bl[12];
    int bid = blockIdx.x, t = threadIdx.x;

    if (bid < 2048) {
        const int n8 = MROWS * CC / 8;
        int i = bid * 256 + t;
        int stride = 2048 * 256;
        for (; i < n8; i += stride) {
            f32x4 a = *(const f32x4*)(x + (size_t)i * 8);
            f32x4 b = *(const f32x4*)(x + (size_t)i * 8 + 4);
            *(bf16x8*)(xb + (size_t)i * 8) = cvt8(a, b);
        }
    } else if (bid < 2912) {
        int i = (bid - 2048) * 256 + t;          // 864*256 == 3*CC*CC/8 exact
        f32x4 a = *(const f32x4*)(wqkv + (size_t)i * 8);
        f32x4 b = *(const f32x4*)(wqkv + (size_t)i * 8 + 4);
        *(bf16x8*)(wb + (size_t)i * 8) = cvt8(a, b);
    } else if (bid < 3200) {
        int i = (bid - 2912) * 256 + t;          // 288*256 == CC*CC/8 exact
        f32x4 a = *(const f32x4*)(wproj + (size_t)i * 8);
        f32x4 b = *(const f32x4*)(wproj + (size_t)i * 8 + 4);
        *(bf16x8*)(wpb + (size_t)i * 8) = cvt8(a, b);
    } else if (bid < 3456) {
        // k0_bias verbatim (n = bid - 3200)
        if (t < 144) wl[t] = wl_[t];
        if (t < 12)  bl[t] = bl_[t];
        __syncthreads();
        int n = bid - 3200;   // 0..255
        int m = t;            // 0..255
        float r[12];
        bool valid = (n < NN) && (m < NN);
        if (valid) {
            int idx = relidx[n * NN + m];
            #pragma unroll
            for (int h = 0; h < 12; ++h) r[h] = rpe[h * NBUCKET + idx];
        }
        #pragma unroll
        for (int g = 0; g < 12; ++g) {
            float o = -30000.f;
            if (valid) {
                o = bl[g];
                #pragma unroll
                for (int h = 0; h < 12; ++h) o += wl[g * 12 + h] * r[h];
            }
            biasb[(size_t)(g * 256 + n) * 256 + m] = (__bf16)o;
        }
    } else {
        // VT pad zero: rows are (b*12+h)*64+d, 0..49151; cols [245,256)
        int row = (bid - 3456) * 256 + t;        // 192*256 == 49152 exact
        __bf16* p = VT + (size_t)row * NP + NN;
        __bf16 z = (__bf16)0.f;
        #pragma unroll
        for (int j = 0; j < 11; ++j) p[j] = z;
    }
}

// ---------------------------------------------------------------------------
// gemm128: m97-structure 128x128-tile NT GEMM (bf16 in, K=768, BK=32).
// R0-verified version verbatim (116.9 us green). GEMM family closed.
template<int EPI>
__global__ __launch_bounds__(256) void gemm128(
    const __bf16* __restrict__ A, const __bf16* __restrict__ Bw,
    __bf16* __restrict__ Q, __bf16* __restrict__ Kb, __bf16* __restrict__ VT,
    const float* __restrict__ bproj, float* __restrict__ outp)
{
    __shared__ __attribute__((aligned(16))) __bf16 sA[128 * 32];
    __shared__ __attribute__((aligned(16))) __bf16 sB[128 * 32];
    int tid = threadIdx.x, lane = tid & 63, wave = tid >> 6;

    // T1: XCD-chunked bijective swizzle
    int gx = gridDim.x;
    int nwg = gx * gridDim.y;
    int wg = blockIdx.y * gx + blockIdx.x;
    int q8 = nwg >> 3, r8 = nwg & 7;
    int xcd = wg & 7, idx = wg >> 3;
    int swz = (xcd < r8 ? xcd * (q8 + 1) : r8 * (q8 + 1) + (xcd - r8) * q8) + idx;
    int et = swz % gx, mt = swz / gx;
    int m0 = mt * 128, e0 = et * 128;

    int r1 = tid >> 2, chunk = tid & 3;
    int gar1 = m0 + r1;        if (gar1 >= MROWS) gar1 = MROWS - 1;
    int gar2 = m0 + 64 + r1;   if (gar2 >= MROWS) gar2 = MROWS - 1;
    const __bf16* aA1 = A  + (size_t)gar1 * CC + chunk * 8;
    const __bf16* aA2 = A  + (size_t)gar2 * CC + chunk * 8;
    const __bf16* aB1 = Bw + (size_t)(e0 + r1) * CC + chunk * 8;
    const __bf16* aB2 = Bw + (size_t)(e0 + 64 + r1) * CC + chunk * 8;
    __bf16* lA1 = sA + tid * 8;
    __bf16* lA2 = sA + tid * 8 + 2048;
    __bf16* lB1 = sB + tid * 8;
    __bf16* lB2 = sB + tid * 8 + 2048;

    int wr = wave >> 1, wc = wave & 1;
    int lrow = lane & 15, lk = (lane >> 4) * 8;
    const __bf16* ra = sA + (wr * 64 + lrow) * 32 + lk;
    const __bf16* rb = sB + (wc * 64 + lrow) * 32 + lk;

    f32x4 acc[4][4];
    #pragma unroll
    for (int q = 0; q < 4; ++q)
        #pragma unroll
        for (int n = 0; n < 4; ++n) acc[q][n] = fzero();

    for (int it = 0; it < 24; ++it) {
        __syncthreads();
        gl_lds16(aA1 + it * 32, lA1);
        gl_lds16(aA2 + it * 32, lA2);
        gl_lds16(aB1 + it * 32, lB1);
        gl_lds16(aB2 + it * 32, lB2);
        __syncthreads();
        bf16x8 af[4], bfr[4];
        #pragma unroll
        for (int q = 0; q < 4; ++q) af[q]  = *(const bf16x8*)(ra + q * 512);
        #pragma unroll
        for (int n = 0; n < 4; ++n) bfr[n] = *(const bf16x8*)(rb + n * 512);
        #pragma unroll
        for (int q = 0; q < 4; ++q)
            #pragma unroll
            for (int n = 0; n < 4; ++n)
                acc[q][n] = MFMA(af[q], bfr[n], acc[q][n]);
    }

    int col = lane & 15, rbs = (lane >> 4) * 4;
    #pragma unroll
    for (int q = 0; q < 4; ++q) {
        int gmb = m0 + wr * 64 + q * 16 + rbs;
        #pragma unroll
        for (int n = 0; n < 4; ++n) {
            int e = e0 + wc * 64 + n * 16 + col;
            if (EPI == 0) {
                int which = e / CC;
                int h = (e % CC) >> 6;
                int d = e & 63;
                #pragma unroll
                for (int r = 0; r < 4; ++r) {
                    int gm = gmb + r;
                    if (gm < MROWS) {
                        int bidx = gm / NN, nn = gm - bidx * NN;
                        float v = acc[q][n][r];
                        if (which == 0)
                            Q[((size_t)(bidx * 12 + h) * NP + nn) * 64 + d] = (__bf16)(v * 0.125f);
                        else if (which == 1)
                            Kb[((size_t)(bidx * 12 + h) * NP + nn) * 64 + d] = (__bf16)v;
                        else
                            VT[((size_t)(bidx * 12 + h) * 64 + d) * NP + nn] = (__bf16)v;
                    }
                }
            } else {
                float bv = bproj[e];
                #pragma unroll
                for (int r = 0; r < 4; ++r) {
                    int gm = gmb + r;
                    if (gm < MROWS)
                        outp[(size_t)gm * CC + e] = acc[q][n][r] + bv;
                }
            }
        }
    }
}

// ---------------------------------------------------------------------------
// K2c: S[b][g][n][m] = sum_h w_l[g,h]*(q_h.k_h) + bias'[g][n][m]  (bf16)
// R15: R13's LDS-staged main loop + bias loads batch-issued at KERNEL START.
// The 48 bias scalar loads are data-dependent 4-segment scattered reads; in
// the R1 epilogue they stall per-g. Addresses depend only on block/lane
// indices, so issuing them all up front hides their latency + segment
// serialization under the 12-h MFMA loop. Same addresses, values, FP order
// => bit-exact. (R12's neutral prefetch predates R13 — main loop then still
// hid the epilogue; now it's a visible fraction of k2c's 66 us.)
__global__ __launch_bounds__(512, 4) void k2c_qk(
    const __bf16* __restrict__ Q, const __bf16* __restrict__ Kb,
    const __bf16* __restrict__ biasb, const float* __restrict__ wl_,
    __bf16* __restrict__ S)
{
    // 96 rows (0-31: Q tile, 32-95: K tile) x 64 els, stride 72 els (144B).
    __shared__ __attribute__((aligned(16))) __bf16 sT[2][96 * 72];   // 27.6 KB
    __shared__ float wl[144];
    int tid = threadIdx.x, wave = tid >> 6, lane = tid & 63;
    if (tid < 144) wl[tid] = wl_[tid];   // covered by first loop barrier

    // XCD swizzle: 2048 blocks, 8 consecutive b per XCD (32 blocks per b).
    int wg = blockIdx.x;
    int L = (wg & 7) * 256 + (wg >> 3);
    int b = L >> 5, rem = L & 31;
    int mq = rem & 3, nt = rem >> 2;          // mq 0..3, nt 0..7
    int wn = wave >> 2, wm = wave & 3;
    int n0b = nt * 32, m0b = mq * 64;
    int n0 = n0b + wn * 16;
    int m0 = m0b + wm * 16;

    // ---- bias prefetch: all 48 loads issued before the main loop ---------
    int col = lane & 15, rb = (lane >> 4) * 4;
    float bv[12][4];
    #pragma unroll
    for (int g = 0; g < 12; ++g)
        #pragma unroll
        for (int r = 0; r < 4; ++r)
            bv[g][r] = (float)biasb[(size_t)(g * 256 + n0 + rb + r) * 256 + m0 + col];

    bool hasQ = (tid < 256);
    int kc = hasQ ? (tid + 256) : (tid - 256);              // K chunk 0..511
    int qsrc = (n0b + (tid >> 3)) * 64 + (tid & 7) * 8;     // elements
    int qdst = (tid >> 3) * 72 + (tid & 7) * 8;
    int ksrc = (m0b + (kc >> 3)) * 64 + (kc & 7) * 8;
    int kdst = (32 + (kc >> 3)) * 72 + (kc & 7) * 8;

    int lrow = lane & 15, lk = (lane >> 4) * 8;
    int aR = (wn * 16 + lrow) * 72 + lk;          // Q fragment base (els)
    int bR = (32 + wm * 16 + lrow) * 72 + lk;     // K fragment base (els)

    f32x4 acc[12];
    #pragma unroll
    for (int h = 0; h < 12; ++h) acc[h] = fzero();

    // prologue: stage h=0 into buf 0
    size_t hb = (size_t)(b * 12) << 14;           // *(NP*64)
    bf16x8 rk = *(const bf16x8*)(Kb + hb + ksrc);
    bf16x8 rq;
    if (hasQ) rq = *(const bf16x8*)(Q + hb + qsrc);
    *(bf16x8*)&sT[0][kdst] = rk;
    if (hasQ) *(bf16x8*)&sT[0][qdst] = rq;

    #pragma unroll
    for (int h = 0; h < 12; ++h) {
        int s = h & 1;
        if (h < 11) {   // issue next-h global loads (regs only, no LDS touch)
            size_t hb2 = (size_t)(b * 12 + h + 1) << 14;
            rk = *(const bf16x8*)(Kb + hb2 + ksrc);
            if (hasQ) rq = *(const bf16x8*)(Q + hb2 + qsrc);
        }
        __syncthreads();   // buf s writes visible; all reads of buf s^1 done
        bf16x8 a0 = *(const bf16x8*)&sT[s][aR];
        bf16x8 a1 = *(const bf16x8*)&sT[s][aR + 32];
        bf16x8 b0 = *(const bf16x8*)&sT[s][bR];
        bf16x8 b1 = *(const bf16x8*)&sT[s][bR + 32];
        acc[h] = MFMA(a0, b0, acc[h]);
        acc[h] = MFMA(a1, b1, acc[h]);
        if (h < 11) {   // write next-h into other buffer (readers done)
            *(bf16x8*)&sT[s ^ 1][kdst] = rk;
            if (hasQ) *(bf16x8*)&sT[s ^ 1][qdst] = rq;
        }
    }

    // ---- epilogue: mix + prefetched bias + store -------------------------
    #pragma unroll
    for (int g = 0; g < 12; ++g) {
        f32x4 s = fzero();
        #pragma unroll
        for (int h = 0; h < 12; ++h) {
            float w = wl[g * 12 + h];
            s += acc[h] * w;
        }
        #pragma unroll
        for (int r = 0; r < 4; ++r) {
            int n = n0 + rb + r;
            int m = m0 + col;
            float v = s[r] + bv[g][r];
            S[((size_t)(b * 12 + g) * NP + n) * NP + m] = (__bf16)v;
        }
    }
}

// ---------------------------------------------------------------------------
// K34 fused: softmax (P in registers) + w_w post-mix + PV MFMA.
// (R14-green VT-staged version verbatim)
__global__ __launch_bounds__(512, 2) void k34_smx_pv(
    const __bf16* __restrict__ S, const __bf16* __restrict__ VT,
    const float* __restrict__ ww_, const float* __restrict__ bw_,
    __bf16* __restrict__ aout)
{
    __shared__ __attribute__((aligned(16))) __bf16 Pp[2][16][264];    // 16.9 KB
    __shared__ __attribute__((aligned(16))) __bf16 VTl[2 * 64 * 256]; // 64 KB
    __shared__ float ww[144];
    __shared__ float bw[12];
    int tid = threadIdx.x;
    if (tid < 144) ww[tid] = ww_[tid];
    if (tid >= 256 && tid < 268) bw[tid - 256] = bw_[tid - 256];

    // XCD swizzle: 16 same-b blocks -> same XCD
    int W = blockIdx.x;                 // 0..1023
    int g8 = W & 7, kk = W >> 3;
    int L = (kk >> 4) * 128 + g8 * 16 + (kk & 15);   // bijective
    int b = L >> 4, nt = L & 15;
    int n0 = nt * 16;

    int n = tid >> 5, ms = tid & 31;
    int lane = tid & 63, wave = tid >> 6;

    // ---- Phase A: per-(g,n)-row softmax; P kept in registers -------------
    float P[12][8];
    #pragma unroll
    for (int g = 0; g < 12; ++g) {
        const __bf16* rowp = S + ((size_t)(b * 12 + g) * NP + n0 + n) * NP + ms * 8;
        bf16x8 sv = *(const bf16x8*)rowp;
        float v[8];
        float mx = -1e30f;
        #pragma unroll
        for (int j = 0; j < 8; ++j) {
            v[j] = (ms * 8 + j < NN) ? (float)sv[j] : -1e30f;
            mx = fmaxf(mx, v[j]);
        }
        #pragma unroll
        for (int o = 16; o > 0; o >>= 1) mx = fmaxf(mx, __shfl_xor(mx, o));
        float sum = 0.f;
        #pragma unroll
        for (int j = 0; j < 8; ++j) {
            float e = (ms * 8 + j < NN) ? __expf(v[j] - mx) : 0.f;
            P[g][j] = e;
            sum += e;
        }
        #pragma unroll
        for (int o = 16; o > 0; o >>= 1) sum += __shfl_xor(sum, o);
        float inv = 1.f / sum;
        #pragma unroll
        for (int j = 0; j < 8; ++j) P[g][j] *= inv;
    }
    __syncthreads();   // also covers ww/bw loads

    // ---- Phase B: 6 chunks of {stage VT, mix 2 gp -> LDS, PV MFMA} -------
    int dt = wave >> 1, wgp = wave & 1;
    int lrow = lane & 15, lk = (lane >> 4) * 8, hh = lane >> 4;
    int col = lane & 15, rb = (lane >> 4) * 4;
    #pragma unroll 1
    for (int c = 0; c < 6; ++c) {
        // stage VT slices for gp = c*2+{0,1}: 4096 16B chunks, linear LDS
        // dest (wave-uniform+lane*16), source-swizzled within 128B spans.
        #pragma unroll
        for (int i = 0; i < 8; ++i) {
            int f = i * 512 + tid;            // 0..4095
            int wgs = f >> 11;                // which gp slice
            int cc = f & 2047;                // chunk within slice
            int row = cc >> 5, pc = cc & 31;
            int lch = pc ^ (row & 7);         // logical chunk at this slot
            const __bf16* src = VT + ((size_t)(b * 12 + c * 2 + wgs) * 64 + row) * NP + lch * 8;
            gl_lds16(src, VTl + (size_t)f * 8);
        }
        // w_w mix -> Pp (hides staging latency)
        #pragma unroll
        for (int gi = 0; gi < 2; ++gi) {
            int gp = c * 2 + gi;
            bf16x8 o;
            #pragma unroll
            for (int j = 0; j < 8; ++j) {
                float a = bw[gp];
                #pragma unroll
                for (int g = 0; g < 12; ++g) a += ww[gp * 12 + g] * P[g][j];
                o[j] = (__bf16)((ms * 8 + j < NN) ? a : 0.f);
            }
            *(bf16x8*)&Pp[gi][n][ms * 8] = o;
        }
        __syncthreads();   // Pp visible + vmcnt drained (VTl staged)
        f32x4 acc = fzero();
        const __bf16* vbase = VTl + (size_t)wgp * 16384 + (dt * 16 + lrow) * 256;
        #pragma unroll
        for (int kt = 0; kt < 8; ++kt) {
            bf16x8 av = *(const bf16x8*)&Pp[wgp][lrow][kt * 32 + lk];
            bf16x8 bv = *(const bf16x8*)(vbase + (((kt * 4 + hh) ^ (lrow & 7)) * 8));
            acc = MFMA(av, bv, acc);
        }
        int gp = c * 2 + wgp;
        #pragma unroll
        for (int r = 0; r < 4; ++r) {
            int gn = n0 + rb + r;
            if (gn < NN)
                aout[((size_t)b * NN + gn) * CC + gp * 64 + dt * 16 + col] = (__bf16)acc[r];
        }
        __syncthreads();   // Pp+VTl consumed; safe to overwrite next chunk
    }
}

// ---------------------------------------------------------------------------
extern "C" void kernel_launch(void* const* d_in, const int* in_sizes, int n_in,
                              void* d_out, int out_size, void* d_ws, size_t ws_size,
                              hipStream_t stream)
{
    (void)in_sizes; (void)n_in; (void)out_size; (void)ws_size;
    const float* x     = (const float*)d_in[0];
    const float* wqkv  = (const float*)d_in[1];
    const float* wproj = (const float*)d_in[2];
    const float* bproj = (const float*)d_in[3];
    const float* wl    = (const float*)d_in[4];
    const float* bl    = (const float*)d_in[5];
    const float* ww    = (const float*)d_in[6];
    const float* bw    = (const float*)d_in[7];
    const float* rpe   = (const float*)d_in[8];
    const int*   rel   = (const int*)d_in[9];

    char* ws = (char*)d_ws;
    const size_t SZ_QKV = (size_t)64 * 12 * 256 * 64 * 2;   // 25,165,824 B
    const size_t SZ_S   = (size_t)64 * 12 * 256 * 256 * 2;  // 100,663,296 B
    __bf16* Q     = (__bf16*)(ws);
    __bf16* Kb    = (__bf16*)(ws + SZ_QKV);
    __bf16* VT    = (__bf16*)(ws + 2 * SZ_QKV);
    __bf16* biasb = (__bf16*)(ws + 3 * SZ_QKV);              // 1.5 MB (bf16)
    char*   sreg  = ws + 3 * SZ_QKV + (size_t)12 * 256 * 256 * 4;
    __bf16* S     = (__bf16*)sreg;
    // xb/wb alias into the S region (dead before k2c writes S)
    __bf16* xb    = (__bf16*)sreg;                               // 24.1 MB
    __bf16* wb    = (__bf16*)(sreg + (size_t)MROWS * CC * 2);    //  3.5 MB
    __bf16* wpb   = (__bf16*)(ws + 3 * SZ_QKV + (size_t)12 * 256 * 256 * 4 + SZ_S);
    __bf16* aout  = Q;  // Q dead after k2c; reuse as attn-out

    // VT pad columns zeroed inside prep (blocks [3456,3648)) — no memset.
    prep<<<dim3(3648), 256, 0, stream>>>(x, xb, wqkv, wb, wproj, wpb,
                                         rpe, rel, wl, bl, biasb, VT);
    gemm128<0><<<dim3(18, 123), 256, 0, stream>>>(xb, wb, Q, Kb, VT, nullptr, nullptr);
    k2c_qk<<<dim3(2048), 512, 0, stream>>>(Q, Kb, biasb, wl, S);
    k34_smx_pv<<<dim3(1024), 512, 0, stream>>>(S, VT, ww, bw, aout);
    gemm128<1><<<dim3(6, 123), 256, 0, stream>>>(aout, wpb, nullptr, nullptr, nullptr,
                                                 bproj, (float*)d_out);
}

// Round 16
// 298.507 us; speedup vs baseline: 1.0244x; 1.0244x over previous
//
#include <hip/hip_runtime.h>
#include <hip/hip_bf16.h>

// Problem constants
#define NN 245      // tokens
#define NP 256      // padded tokens
#define HH 12       // heads
#define DD 64       // head dim
#define CC 768      // channels
#define NBUCKET 1698
#define MROWS (64 * NN)   // 15680

typedef __bf16 bf16x8 __attribute__((ext_vector_type(8)));
typedef float f32x4 __attribute__((ext_vector_type(4)));

#define MFMA(a, b, c) __builtin_amdgcn_mfma_f32_16x16x32_bf16(a, b, c, 0, 0, 0)

static __device__ __forceinline__ f32x4 fzero() {
    f32x4 z = {0.f, 0.f, 0.f, 0.f};
    return z;
}

static __device__ __forceinline__ bf16x8 cvt8(f32x4 lo, f32x4 hi) {
    bf16x8 r;
    #pragma unroll
    for (int i = 0; i < 4; ++i) { r[i] = (__bf16)lo[i]; r[i + 4] = (__bf16)hi[i]; }
    return r;
}

// async global->LDS, 16B per lane (wave-uniform LDS base + lane*16)
static __device__ __forceinline__ void gl_lds16(const __bf16* g, __bf16* l) {
    __builtin_amdgcn_global_load_lds(
        (const __attribute__((address_space(1))) void*)g,
        (__attribute__((address_space(3))) void*)l, 16, 0, 0);
}

// ---------------------------------------------------------------------------
// PREP (one launch, 3648 blocks of 256): 4 independent prep tasks concurrent
// + VT pad-column zeroing. (R10-green version verbatim)
__global__ __launch_bounds__(256) void prep(
    const float* __restrict__ x,     __bf16* __restrict__ xb,
    const float* __restrict__ wqkv,  __bf16* __restrict__ wb,
    const float* __restrict__ wproj, __bf16* __restrict__ wpb,
    const float* __restrict__ rpe, const int* __restrict__ relidx,
    const float* __restrict__ wl_, const float* __restrict__ bl_,
    __bf16* __restrict__ biasb, __bf16* __restrict__ VT)
{
    __shared__ float wl[144];
    __shared__ float bl[12];
    int bid = blockIdx.x, t = threadIdx.x;

    if (bid < 2048) {
        const int n8 = MROWS * CC / 8;
        int i = bid * 256 + t;
        int stride = 2048 * 256;
        for (; i < n8; i += stride) {
            f32x4 a = *(const f32x4*)(x + (size_t)i * 8);
            f32x4 b = *(const f32x4*)(x + (size_t)i * 8 + 4);
            *(bf16x8*)(xb + (size_t)i * 8) = cvt8(a, b);
        }
    } else if (bid < 2912) {
        int i = (bid - 2048) * 256 + t;          // 864*256 == 3*CC*CC/8 exact
        f32x4 a = *(const f32x4*)(wqkv + (size_t)i * 8);
        f32x4 b = *(const f32x4*)(wqkv + (size_t)i * 8 + 4);
        *(bf16x8*)(wb + (size_t)i * 8) = cvt8(a, b);
    } else if (bid < 3200) {
        int i = (bid - 2912) * 256 + t;          // 288*256 == CC*CC/8 exact
        f32x4 a = *(const f32x4*)(wproj + (size_t)i * 8);
        f32x4 b = *(const f32x4*)(wproj + (size_t)i * 8 + 4);
        *(bf16x8*)(wpb + (size_t)i * 8) = cvt8(a, b);
    } else if (bid < 3456) {
        // k0_bias verbatim (n = bid - 3200)
        if (t < 144) wl[t] = wl_[t];
        if (t < 12)  bl[t] = bl_[t];
        __syncthreads();
        int n = bid - 3200;   // 0..255
        int m = t;            // 0..255
        float r[12];
        bool valid = (n < NN) && (m < NN);
        if (valid) {
            int idx = relidx[n * NN + m];
            #pragma unroll
            for (int h = 0; h < 12; ++h) r[h] = rpe[h * NBUCKET + idx];
        }
        #pragma unroll
        for (int g = 0; g < 12; ++g) {
            float o = -30000.f;
            if (valid) {
                o = bl[g];
                #pragma unroll
                for (int h = 0; h < 12; ++h) o += wl[g * 12 + h] * r[h];
            }
            biasb[(size_t)(g * 256 + n) * 256 + m] = (__bf16)o;
        }
    } else {
        // VT pad zero: rows are (b*12+h)*64+d, 0..49151; cols [245,256)
        int row = (bid - 3456) * 256 + t;        // 192*256 == 49152 exact
        __bf16* p = VT + (size_t)row * NP + NN;
        __bf16 z = (__bf16)0.f;
        #pragma unroll
        for (int j = 0; j < 11; ++j) p[j] = z;
    }
}

// ---------------------------------------------------------------------------
// gemm128: m97-structure 128x128-tile NT GEMM (bf16 in, K=768, BK=32).
// R0-verified version verbatim (116.9 us green). GEMM family closed.
template<int EPI>
__global__ __launch_bounds__(256) void gemm128(
    const __bf16* __restrict__ A, const __bf16* __restrict__ Bw,
    __bf16* __restrict__ Q, __bf16* __restrict__ Kb, __bf16* __restrict__ VT,
    const float* __restrict__ bproj, float* __restrict__ outp)
{
    __shared__ __attribute__((aligned(16))) __bf16 sA[128 * 32];
    __shared__ __attribute__((aligned(16))) __bf16 sB[128 * 32];
    int tid = threadIdx.x, lane = tid & 63, wave = tid >> 6;

    // T1: XCD-chunked bijective swizzle
    int gx = gridDim.x;
    int nwg = gx * gridDim.y;
    int wg = blockIdx.y * gx + blockIdx.x;
    int q8 = nwg >> 3, r8 = nwg & 7;
    int xcd = wg & 7, idx = wg >> 3;
    int swz = (xcd < r8 ? xcd * (q8 + 1) : r8 * (q8 + 1) + (xcd - r8) * q8) + idx;
    int et = swz % gx, mt = swz / gx;
    int m0 = mt * 128, e0 = et * 128;

    int r1 = tid >> 2, chunk = tid & 3;
    int gar1 = m0 + r1;        if (gar1 >= MROWS) gar1 = MROWS - 1;
    int gar2 = m0 + 64 + r1;   if (gar2 >= MROWS) gar2 = MROWS - 1;
    const __bf16* aA1 = A  + (size_t)gar1 * CC + chunk * 8;
    const __bf16* aA2 = A  + (size_t)gar2 * CC + chunk * 8;
    const __bf16* aB1 = Bw + (size_t)(e0 + r1) * CC + chunk * 8;
    const __bf16* aB2 = Bw + (size_t)(e0 + 64 + r1) * CC + chunk * 8;
    __bf16* lA1 = sA + tid * 8;
    __bf16* lA2 = sA + tid * 8 + 2048;
    __bf16* lB1 = sB + tid * 8;
    __bf16* lB2 = sB + tid * 8 + 2048;

    int wr = wave >> 1, wc = wave & 1;
    int lrow = lane & 15, lk = (lane >> 4) * 8;
    const __bf16* ra = sA + (wr * 64 + lrow) * 32 + lk;
    const __bf16* rb = sB + (wc * 64 + lrow) * 32 + lk;

    f32x4 acc[4][4];
    #pragma unroll
    for (int q = 0; q < 4; ++q)
        #pragma unroll
        for (int n = 0; n < 4; ++n) acc[q][n] = fzero();

    for (int it = 0; it < 24; ++it) {
        __syncthreads();
        gl_lds16(aA1 + it * 32, lA1);
        gl_lds16(aA2 + it * 32, lA2);
        gl_lds16(aB1 + it * 32, lB1);
        gl_lds16(aB2 + it * 32, lB2);
        __syncthreads();
        bf16x8 af[4], bfr[4];
        #pragma unroll
        for (int q = 0; q < 4; ++q) af[q]  = *(const bf16x8*)(ra + q * 512);
        #pragma unroll
        for (int n = 0; n < 4; ++n) bfr[n] = *(const bf16x8*)(rb + n * 512);
        #pragma unroll
        for (int q = 0; q < 4; ++q)
            #pragma unroll
            for (int n = 0; n < 4; ++n)
                acc[q][n] = MFMA(af[q], bfr[n], acc[q][n]);
    }

    int col = lane & 15, rbs = (lane >> 4) * 4;
    #pragma unroll
    for (int q = 0; q < 4; ++q) {
        int gmb = m0 + wr * 64 + q * 16 + rbs;
        #pragma unroll
        for (int n = 0; n < 4; ++n) {
            int e = e0 + wc * 64 + n * 16 + col;
            if (EPI == 0) {
                int which = e / CC;
                int h = (e % CC) >> 6;
                int d = e & 63;
                #pragma unroll
                for (int r = 0; r < 4; ++r) {
                    int gm = gmb + r;
                    if (gm < MROWS) {
                        int bidx = gm / NN, nn = gm - bidx * NN;
                        float v = acc[q][n][r];
                        if (which == 0)
                            Q[((size_t)(bidx * 12 + h) * NP + nn) * 64 + d] = (__bf16)(v * 0.125f);
                        else if (which == 1)
                            Kb[((size_t)(bidx * 12 + h) * NP + nn) * 64 + d] = (__bf16)v;
                        else
                            VT[((size_t)(bidx * 12 + h) * 64 + d) * NP + nn] = (__bf16)v;
                    }
                }
            } else {
                float bv = bproj[e];
                #pragma unroll
                for (int r = 0; r < 4; ++r) {
                    int gm = gmb + r;
                    if (gm < MROWS)
                        outp[(size_t)gm * CC + e] = acc[q][n][r] + bv;
                }
            }
        }
    }
}

// ---------------------------------------------------------------------------
// K2c: S[b][g][n][m] = sum_h w_l[g,h]*(q_h.k_h) + bias'[g][n][m]  (bf16)
// (R13/R14-green LDS-staged version verbatim: coalesced staging killed the
// 16-segment fragment-load serialization; 115 -> ~66 us. R15's bias
// prefetch regressed (+6.5 us total) — register pressure across the main
// loop outweighed hidden epilogue latency; reverted. k2c closed.)
__global__ __launch_bounds__(512, 4) void k2c_qk(
    const __bf16* __restrict__ Q, const __bf16* __restrict__ Kb,
    const __bf16* __restrict__ biasb, const float* __restrict__ wl_,
    __bf16* __restrict__ S)
{
    // 96 rows (0-31: Q tile, 32-95: K tile) x 64 els, stride 72 els (144B).
    __shared__ __attribute__((aligned(16))) __bf16 sT[2][96 * 72];   // 27.6 KB
    __shared__ float wl[144];
    int tid = threadIdx.x, wave = tid >> 6, lane = tid & 63;
    if (tid < 144) wl[tid] = wl_[tid];   // covered by first loop barrier

    // XCD swizzle: 2048 blocks, 8 consecutive b per XCD (32 blocks per b).
    int wg = blockIdx.x;
    int L = (wg & 7) * 256 + (wg >> 3);
    int b = L >> 5, rem = L & 31;
    int mq = rem & 3, nt = rem >> 2;          // mq 0..3, nt 0..7
    int wn = wave >> 2, wm = wave & 3;
    int n0b = nt * 32, m0b = mq * 64;
    int n0 = n0b + wn * 16;
    int m0 = m0b + wm * 16;

    bool hasQ = (tid < 256);
    int kc = hasQ ? (tid + 256) : (tid - 256);              // K chunk 0..511
    int qsrc = (n0b + (tid >> 3)) * 64 + (tid & 7) * 8;     // elements
    int qdst = (tid >> 3) * 72 + (tid & 7) * 8;
    int ksrc = (m0b + (kc >> 3)) * 64 + (kc & 7) * 8;
    int kdst = (32 + (kc >> 3)) * 72 + (kc & 7) * 8;

    int lrow = lane & 15, lk = (lane >> 4) * 8;
    int aR = (wn * 16 + lrow) * 72 + lk;          // Q fragment base (els)
    int bR = (32 + wm * 16 + lrow) * 72 + lk;     // K fragment base (els)

    f32x4 acc[12];
    #pragma unroll
    for (int h = 0; h < 12; ++h) acc[h] = fzero();

    // prologue: stage h=0 into buf 0
    size_t hb = (size_t)(b * 12) << 14;           // *(NP*64)
    bf16x8 rk = *(const bf16x8*)(Kb + hb + ksrc);
    bf16x8 rq;
    if (hasQ) rq = *(const bf16x8*)(Q + hb + qsrc);
    *(bf16x8*)&sT[0][kdst] = rk;
    if (hasQ) *(bf16x8*)&sT[0][qdst] = rq;

    #pragma unroll
    for (int h = 0; h < 12; ++h) {
        int s = h & 1;
        if (h < 11) {   // issue next-h global loads (regs only, no LDS touch)
            size_t hb2 = (size_t)(b * 12 + h + 1) << 14;
            rk = *(const bf16x8*)(Kb + hb2 + ksrc);
            if (hasQ) rq = *(const bf16x8*)(Q + hb2 + qsrc);
        }
        __syncthreads();   // buf s writes visible; all reads of buf s^1 done
        bf16x8 a0 = *(const bf16x8*)&sT[s][aR];
        bf16x8 a1 = *(const bf16x8*)&sT[s][aR + 32];
        bf16x8 b0 = *(const bf16x8*)&sT[s][bR];
        bf16x8 b1 = *(const bf16x8*)&sT[s][bR + 32];
        acc[h] = MFMA(a0, b0, acc[h]);
        acc[h] = MFMA(a1, b1, acc[h]);
        if (h < 11) {   // write next-h into other buffer (readers done)
            *(bf16x8*)&sT[s ^ 1][kdst] = rk;
            if (hasQ) *(bf16x8*)&sT[s ^ 1][qdst] = rq;
        }
    }

    // ---- epilogue: R1-verbatim mix + bias + store ------------------------
    int col = lane & 15, rb = (lane >> 4) * 4;
    #pragma unroll
    for (int g = 0; g < 12; ++g) {
        f32x4 s = fzero();
        #pragma unroll
        for (int h = 0; h < 12; ++h) {
            float w = wl[g * 12 + h];
            s += acc[h] * w;
        }
        #pragma unroll
        for (int r = 0; r < 4; ++r) {
            int n = n0 + rb + r;
            int m = m0 + col;
            float v = s[r] + (float)biasb[(size_t)(g * 256 + n) * 256 + m];
            S[((size_t)(b * 12 + g) * NP + n) * NP + m] = (__bf16)v;
        }
    }
}

// ---------------------------------------------------------------------------
// K34 fused: softmax (P in registers) + w_w post-mix + PV MFMA.
// (R14-green VT-staged version verbatim: VT slices staged via
// global_load_lds with source-side XOR swizzle within 128B spans; fragment
// ds_read_b128 2-way banked; staging hidden under the w_w mix. 78 -> ~64 us)
__global__ __launch_bounds__(512, 2) void k34_smx_pv(
    const __bf16* __restrict__ S, const __bf16* __restrict__ VT,
    const float* __restrict__ ww_, const float* __restrict__ bw_,
    __bf16* __restrict__ aout)
{
    __shared__ __attribute__((aligned(16))) __bf16 Pp[2][16][264];    // 16.9 KB
    __shared__ __attribute__((aligned(16))) __bf16 VTl[2 * 64 * 256]; // 64 KB
    __shared__ float ww[144];
    __shared__ float bw[12];
    int tid = threadIdx.x;
    if (tid < 144) ww[tid] = ww_[tid];
    if (tid >= 256 && tid < 268) bw[tid - 256] = bw_[tid - 256];

    // XCD swizzle: 16 same-b blocks -> same XCD
    int W = blockIdx.x;                 // 0..1023
    int g8 = W & 7, kk = W >> 3;
    int L = (kk >> 4) * 128 + g8 * 16 + (kk & 15);   // bijective
    int b = L >> 4, nt = L & 15;
    int n0 = nt * 16;

    int n = tid >> 5, ms = tid & 31;
    int lane = tid & 63, wave = tid >> 6;

    // ---- Phase A: per-(g,n)-row softmax; P kept in registers -------------
    float P[12][8];
    #pragma unroll
    for (int g = 0; g < 12; ++g) {
        const __bf16* rowp = S + ((size_t)(b * 12 + g) * NP + n0 + n) * NP + ms * 8;
        bf16x8 sv = *(const bf16x8*)rowp;
        float v[8];
        float mx = -1e30f;
        #pragma unroll
        for (int j = 0; j < 8; ++j) {
            v[j] = (ms * 8 + j < NN) ? (float)sv[j] : -1e30f;
            mx = fmaxf(mx, v[j]);
        }
        #pragma unroll
        for (int o = 16; o > 0; o >>= 1) mx = fmaxf(mx, __shfl_xor(mx, o));
        float sum = 0.f;
        #pragma unroll
        for (int j = 0; j < 8; ++j) {
            float e = (ms * 8 + j < NN) ? __expf(v[j] - mx) : 0.f;
            P[g][j] = e;
            sum += e;
        }
        #pragma unroll
        for (int o = 16; o > 0; o >>= 1) sum += __shfl_xor(sum, o);
        float inv = 1.f / sum;
        #pragma unroll
        for (int j = 0; j < 8; ++j) P[g][j] *= inv;
    }
    __syncthreads();   // also covers ww/bw loads

    // ---- Phase B: 6 chunks of {stage VT, mix 2 gp -> LDS, PV MFMA} -------
    int dt = wave >> 1, wgp = wave & 1;
    int lrow = lane & 15, lk = (lane >> 4) * 8, hh = lane >> 4;
    int col = lane & 15, rb = (lane >> 4) * 4;
    #pragma unroll 1
    for (int c = 0; c < 6; ++c) {
        // stage VT slices for gp = c*2+{0,1}: 4096 16B chunks, linear LDS
        // dest (wave-uniform+lane*16), source-swizzled within 128B spans.
        #pragma unroll
        for (int i = 0; i < 8; ++i) {
            int f = i * 512 + tid;            // 0..4095
            int wgs = f >> 11;                // which gp slice
            int cc = f & 2047;                // chunk within slice
            int row = cc >> 5, pc = cc & 31;
            int lch = pc ^ (row & 7);         // logical chunk at this slot
            const __bf16* src = VT + ((size_t)(b * 12 + c * 2 + wgs) * 64 + row) * NP + lch * 8;
            gl_lds16(src, VTl + (size_t)f * 8);
        }
        // w_w mix -> Pp (hides staging latency)
        #pragma unroll
        for (int gi = 0; gi < 2; ++gi) {
            int gp = c * 2 + gi;
            bf16x8 o;
            #pragma unroll
            for (int j = 0; j < 8; ++j) {
                float a = bw[gp];
                #pragma unroll
                for (int g = 0; g < 12; ++g) a += ww[gp * 12 + g] * P[g][j];
                o[j] = (__bf16)((ms * 8 + j < NN) ? a : 0.f);
            }
            *(bf16x8*)&Pp[gi][n][ms * 8] = o;
        }
        __syncthreads();   // Pp visible + vmcnt drained (VTl staged)
        f32x4 acc = fzero();
        const __bf16* vbase = VTl + (size_t)wgp * 16384 + (dt * 16 + lrow) * 256;
        #pragma unroll
        for (int kt = 0; kt < 8; ++kt) {
            bf16x8 av = *(const bf16x8*)&Pp[wgp][lrow][kt * 32 + lk];
            bf16x8 bv = *(const bf16x8*)(vbase + (((kt * 4 + hh) ^ (lrow & 7)) * 8));
            acc = MFMA(av, bv, acc);
        }
        int gp = c * 2 + wgp;
        #pragma unroll
        for (int r = 0; r < 4; ++r) {
            int gn = n0 + rb + r;
            if (gn < NN)
                aout[((size_t)b * NN + gn) * CC + gp * 64 + dt * 16 + col] = (__bf16)acc[r];
        }
        __syncthreads();   // Pp+VTl consumed; safe to overwrite next chunk
    }
}

// ---------------------------------------------------------------------------
extern "C" void kernel_launch(void* const* d_in, const int* in_sizes, int n_in,
                              void* d_out, int out_size, void* d_ws, size_t ws_size,
                              hipStream_t stream)
{
    (void)in_sizes; (void)n_in; (void)out_size; (void)ws_size;
    const float* x     = (const float*)d_in[0];
    const float* wqkv  = (const float*)d_in[1];
    const float* wproj = (const float*)d_in[2];
    const float* bproj = (const float*)d_in[3];
    const float* wl    = (const float*)d_in[4];
    const float* bl    = (const float*)d_in[5];
    const float* ww    = (const float*)d_in[6];
    const float* bw    = (const float*)d_in[7];
    const float* rpe   = (const float*)d_in[8];
    const int*   rel   = (const int*)d_in[9];

    char* ws = (char*)d_ws;
    const size_t SZ_QKV = (size_t)64 * 12 * 256 * 64 * 2;   // 25,165,824 B
    const size_t SZ_S   = (size_t)64 * 12 * 256 * 256 * 2;  // 100,663,296 B
    __bf16* Q     = (__bf16*)(ws);
    __bf16* Kb    = (__bf16*)(ws + SZ_QKV);
    __bf16* VT    = (__bf16*)(ws + 2 * SZ_QKV);
    __bf16* biasb = (__bf16*)(ws + 3 * SZ_QKV);              // 1.5 MB (bf16)
    char*   sreg  = ws + 3 * SZ_QKV + (size_t)12 * 256 * 256 * 4;
    __bf16* S     = (__bf16*)sreg;
    // xb/wb alias into the S region (dead before k2c writes S)
    __bf16* xb    = (__bf16*)sreg;                               // 24.1 MB
    __bf16* wb    = (__bf16*)(sreg + (size_t)MROWS * CC * 2);    //  3.5 MB
    __bf16* wpb   = (__bf16*)(ws + 3 * SZ_QKV + (size_t)12 * 256 * 256 * 4 + SZ_S);
    __bf16* aout  = Q;  // Q dead after k2c; reuse as attn-out

    // VT pad columns zeroed inside prep (blocks [3456,3648)) — no memset.
    prep<<<dim3(3648), 256, 0, stream>>>(x, xb, wqkv, wb, wproj, wpb,
                                         rpe, rel, wl, bl, biasb, VT);
    gemm128<0><<<dim3(18, 123), 256, 0, stream>>>(xb, wb, Q, Kb, VT, nullptr, nullptr);
    k2c_qk<<<dim3(2048), 512, 0, stream>>>(Q, Kb, biasb, wl, S);
    k34_smx_pv<<<dim3(1024), 512, 0, stream>>>(S, VT, ww, bw, aout);
    gemm128<1><<<dim3(6, 123), 256, 0, stream>>>(aout, wpb, nullptr, nullptr, nullptr,
                                                 bproj, (float*)d_out);
}

// Round 17
// 298.469 us; speedup vs baseline: 1.0245x; 1.0001x over previous
//
#include <hip/hip_runtime.h>
#include <hip/hip_bf16.h>

// Problem constants
#define NN 245      // tokens
#define NP 256      // padded tokens
#define HH 12       // heads
#define DD 64       // head dim
#define CC 768      // channels
#define NBUCKET 1698
#define MROWS (64 * NN)   // 15680

typedef __bf16 bf16x8 __attribute__((ext_vector_type(8)));
typedef float f32x4 __attribute__((ext_vector_type(4)));

#define MFMA(a, b, c) __builtin_amdgcn_mfma_f32_16x16x32_bf16(a, b, c, 0, 0, 0)

static __device__ __forceinline__ f32x4 fzero() {
    f32x4 z = {0.f, 0.f, 0.f, 0.f};
    return z;
}

static __device__ __forceinline__ bf16x8 cvt8(f32x4 lo, f32x4 hi) {
    bf16x8 r;
    #pragma unroll
    for (int i = 0; i < 4; ++i) { r[i] = (__bf16)lo[i]; r[i + 4] = (__bf16)hi[i]; }
    return r;
}

// async global->LDS, 16B per lane (wave-uniform LDS base + lane*16)
static __device__ __forceinline__ void gl_lds16(const __bf16* g, __bf16* l) {
    __builtin_amdgcn_global_load_lds(
        (const __attribute__((address_space(1))) void*)g,
        (__attribute__((address_space(3))) void*)l, 16, 0, 0);
}

// ---------------------------------------------------------------------------
// PREP (one launch, 3648 blocks of 256): 4 independent prep tasks concurrent
// + VT pad-column zeroing. (R10-green version verbatim)
__global__ __launch_bounds__(256) void prep(
    const float* __restrict__ x,     __bf16* __restrict__ xb,
    const float* __restrict__ wqkv,  __bf16* __restrict__ wb,
    const float* __restrict__ wproj, __bf16* __restrict__ wpb,
    const float* __restrict__ rpe, const int* __restrict__ relidx,
    const float* __restrict__ wl_, const float* __restrict__ bl_,
    __bf16* __restrict__ biasb, __bf16* __restrict__ VT)
{
    __shared__ float wl[144];
    __shared__ float bl[12];
    int bid = blockIdx.x, t = threadIdx.x;

    if (bid < 2048) {
        const int n8 = MROWS * CC / 8;
        int i = bid * 256 + t;
        int stride = 2048 * 256;
        for (; i < n8; i += stride) {
            f32x4 a = *(const f32x4*)(x + (size_t)i * 8);
            f32x4 b = *(const f32x4*)(x + (size_t)i * 8 + 4);
            *(bf16x8*)(xb + (size_t)i * 8) = cvt8(a, b);
        }
    } else if (bid < 2912) {
        int i = (bid - 2048) * 256 + t;          // 864*256 == 3*CC*CC/8 exact
        f32x4 a = *(const f32x4*)(wqkv + (size_t)i * 8);
        f32x4 b = *(const f32x4*)(wqkv + (size_t)i * 8 + 4);
        *(bf16x8*)(wb + (size_t)i * 8) = cvt8(a, b);
    } else if (bid < 3200) {
        int i = (bid - 2912) * 256 + t;          // 288*256 == CC*CC/8 exact
        f32x4 a = *(const f32x4*)(wproj + (size_t)i * 8);
        f32x4 b = *(const f32x4*)(wproj + (size_t)i * 8 + 4);
        *(bf16x8*)(wpb + (size_t)i * 8) = cvt8(a, b);
    } else if (bid < 3456) {
        // k0_bias verbatim (n = bid - 3200)
        if (t < 144) wl[t] = wl_[t];
        if (t < 12)  bl[t] = bl_[t];
        __syncthreads();
        int n = bid - 3200;   // 0..255
        int m = t;            // 0..255
        float r[12];
        bool valid = (n < NN) && (m < NN);
        if (valid) {
            int idx = relidx[n * NN + m];
            #pragma unroll
            for (int h = 0; h < 12; ++h) r[h] = rpe[h * NBUCKET + idx];
        }
        #pragma unroll
        for (int g = 0; g < 12; ++g) {
            float o = -30000.f;
            if (valid) {
                o = bl[g];
                #pragma unroll
                for (int h = 0; h < 12; ++h) o += wl[g * 12 + h] * r[h];
            }
            biasb[(size_t)(g * 256 + n) * 256 + m] = (__bf16)o;
        }
    } else {
        // VT pad zero: rows are (b*12+h)*64+d, 0..49151; cols [245,256)
        int row = (bid - 3456) * 256 + t;        // 192*256 == 49152 exact
        __bf16* p = VT + (size_t)row * NP + NN;
        __bf16 z = (__bf16)0.f;
        #pragma unroll
        for (int j = 0; j < 11; ++j) p[j] = z;
    }
}

// ---------------------------------------------------------------------------
// gemm128: m97-structure 128x128-tile NT GEMM (bf16 in, K=768, BK=32).
// R0-verified math verbatim. R17: __launch_bounds__(256, 3) — regs are
// ~140 unified (76 VGPR + 64 AGPR), under the 170 cap for 3 waves/SIMD,
// yet measured occupancy was ~2 blocks/CU. Explicit min-waves hint targets
// 3 co-resident blocks (+50% cross-block latency hiding, the m114
// mechanism). Math untouched => bit-exact.
template<int EPI>
__global__ __launch_bounds__(256, 3) void gemm128(
    const __bf16* __restrict__ A, const __bf16* __restrict__ Bw,
    __bf16* __restrict__ Q, __bf16* __restrict__ Kb, __bf16* __restrict__ VT,
    const float* __restrict__ bproj, float* __restrict__ outp)
{
    __shared__ __attribute__((aligned(16))) __bf16 sA[128 * 32];
    __shared__ __attribute__((aligned(16))) __bf16 sB[128 * 32];
    int tid = threadIdx.x, lane = tid & 63, wave = tid >> 6;

    // T1: XCD-chunked bijective swizzle
    int gx = gridDim.x;
    int nwg = gx * gridDim.y;
    int wg = blockIdx.y * gx + blockIdx.x;
    int q8 = nwg >> 3, r8 = nwg & 7;
    int xcd = wg & 7, idx = wg >> 3;
    int swz = (xcd < r8 ? xcd * (q8 + 1) : r8 * (q8 + 1) + (xcd - r8) * q8) + idx;
    int et = swz % gx, mt = swz / gx;
    int m0 = mt * 128, e0 = et * 128;

    int r1 = tid >> 2, chunk = tid & 3;
    int gar1 = m0 + r1;        if (gar1 >= MROWS) gar1 = MROWS - 1;
    int gar2 = m0 + 64 + r1;   if (gar2 >= MROWS) gar2 = MROWS - 1;
    const __bf16* aA1 = A  + (size_t)gar1 * CC + chunk * 8;
    const __bf16* aA2 = A  + (size_t)gar2 * CC + chunk * 8;
    const __bf16* aB1 = Bw + (size_t)(e0 + r1) * CC + chunk * 8;
    const __bf16* aB2 = Bw + (size_t)(e0 + 64 + r1) * CC + chunk * 8;
    __bf16* lA1 = sA + tid * 8;
    __bf16* lA2 = sA + tid * 8 + 2048;
    __bf16* lB1 = sB + tid * 8;
    __bf16* lB2 = sB + tid * 8 + 2048;

    int wr = wave >> 1, wc = wave & 1;
    int lrow = lane & 15, lk = (lane >> 4) * 8;
    const __bf16* ra = sA + (wr * 64 + lrow) * 32 + lk;
    const __bf16* rb = sB + (wc * 64 + lrow) * 32 + lk;

    f32x4 acc[4][4];
    #pragma unroll
    for (int q = 0; q < 4; ++q)
        #pragma unroll
        for (int n = 0; n < 4; ++n) acc[q][n] = fzero();

    for (int it = 0; it < 24; ++it) {
        __syncthreads();
        gl_lds16(aA1 + it * 32, lA1);
        gl_lds16(aA2 + it * 32, lA2);
        gl_lds16(aB1 + it * 32, lB1);
        gl_lds16(aB2 + it * 32, lB2);
        __syncthreads();
        bf16x8 af[4], bfr[4];
        #pragma unroll
        for (int q = 0; q < 4; ++q) af[q]  = *(const bf16x8*)(ra + q * 512);
        #pragma unroll
        for (int n = 0; n < 4; ++n) bfr[n] = *(const bf16x8*)(rb + n * 512);
        #pragma unroll
        for (int q = 0; q < 4; ++q)
            #pragma unroll
            for (int n = 0; n < 4; ++n)
                acc[q][n] = MFMA(af[q], bfr[n], acc[q][n]);
    }

    int col = lane & 15, rbs = (lane >> 4) * 4;
    #pragma unroll
    for (int q = 0; q < 4; ++q) {
        int gmb = m0 + wr * 64 + q * 16 + rbs;
        #pragma unroll
        for (int n = 0; n < 4; ++n) {
            int e = e0 + wc * 64 + n * 16 + col;
            if (EPI == 0) {
                int which = e / CC;
                int h = (e % CC) >> 6;
                int d = e & 63;
                #pragma unroll
                for (int r = 0; r < 4; ++r) {
                    int gm = gmb + r;
                    if (gm < MROWS) {
                        int bidx = gm / NN, nn = gm - bidx * NN;
                        float v = acc[q][n][r];
                        if (which == 0)
                            Q[((size_t)(bidx * 12 + h) * NP + nn) * 64 + d] = (__bf16)(v * 0.125f);
                        else if (which == 1)
                            Kb[((size_t)(bidx * 12 + h) * NP + nn) * 64 + d] = (__bf16)v;
                        else
                            VT[((size_t)(bidx * 12 + h) * 64 + d) * NP + nn] = (__bf16)v;
                    }
                }
            } else {
                float bv = bproj[e];
                #pragma unroll
                for (int r = 0; r < 4; ++r) {
                    int gm = gmb + r;
                    if (gm < MROWS)
                        outp[(size_t)gm * CC + e] = acc[q][n][r] + bv;
                }
            }
        }
    }
}

// ---------------------------------------------------------------------------
// K2c: S[b][g][n][m] = sum_h w_l[g,h]*(q_h.k_h) + bias'[g][n][m]  (bf16)
// (R13/R14-green LDS-staged version verbatim; k2c closed.)
__global__ __launch_bounds__(512, 4) void k2c_qk(
    const __bf16* __restrict__ Q, const __bf16* __restrict__ Kb,
    const __bf16* __restrict__ biasb, const float* __restrict__ wl_,
    __bf16* __restrict__ S)
{
    // 96 rows (0-31: Q tile, 32-95: K tile) x 64 els, stride 72 els (144B).
    __shared__ __attribute__((aligned(16))) __bf16 sT[2][96 * 72];   // 27.6 KB
    __shared__ float wl[144];
    int tid = threadIdx.x, wave = tid >> 6, lane = tid & 63;
    if (tid < 144) wl[tid] = wl_[tid];   // covered by first loop barrier

    // XCD swizzle: 2048 blocks, 8 consecutive b per XCD (32 blocks per b).
    int wg = blockIdx.x;
    int L = (wg & 7) * 256 + (wg >> 3);
    int b = L >> 5, rem = L & 31;
    int mq = rem & 3, nt = rem >> 2;          // mq 0..3, nt 0..7
    int wn = wave >> 2, wm = wave & 3;
    int n0b = nt * 32, m0b = mq * 64;
    int n0 = n0b + wn * 16;
    int m0 = m0b + wm * 16;

    bool hasQ = (tid < 256);
    int kc = hasQ ? (tid + 256) : (tid - 256);              // K chunk 0..511
    int qsrc = (n0b + (tid >> 3)) * 64 + (tid & 7) * 8;     // elements
    int qdst = (tid >> 3) * 72 + (tid & 7) * 8;
    int ksrc = (m0b + (kc >> 3)) * 64 + (kc & 7) * 8;
    int kdst = (32 + (kc >> 3)) * 72 + (kc & 7) * 8;

    int lrow = lane & 15, lk = (lane >> 4) * 8;
    int aR = (wn * 16 + lrow) * 72 + lk;          // Q fragment base (els)
    int bR = (32 + wm * 16 + lrow) * 72 + lk;     // K fragment base (els)

    f32x4 acc[12];
    #pragma unroll
    for (int h = 0; h < 12; ++h) acc[h] = fzero();

    // prologue: stage h=0 into buf 0
    size_t hb = (size_t)(b * 12) << 14;           // *(NP*64)
    bf16x8 rk = *(const bf16x8*)(Kb + hb + ksrc);
    bf16x8 rq;
    if (hasQ) rq = *(const bf16x8*)(Q + hb + qsrc);
    *(bf16x8*)&sT[0][kdst] = rk;
    if (hasQ) *(bf16x8*)&sT[0][qdst] = rq;

    #pragma unroll
    for (int h = 0; h < 12; ++h) {
        int s = h & 1;
        if (h < 11) {   // issue next-h global loads (regs only, no LDS touch)
            size_t hb2 = (size_t)(b * 12 + h + 1) << 14;
            rk = *(const bf16x8*)(Kb + hb2 + ksrc);
            if (hasQ) rq = *(const bf16x8*)(Q + hb2 + qsrc);
        }
        __syncthreads();   // buf s writes visible; all reads of buf s^1 done
        bf16x8 a0 = *(const bf16x8*)&sT[s][aR];
        bf16x8 a1 = *(const bf16x8*)&sT[s][aR + 32];
        bf16x8 b0 = *(const bf16x8*)&sT[s][bR];
        bf16x8 b1 = *(const bf16x8*)&sT[s][bR + 32];
        acc[h] = MFMA(a0, b0, acc[h]);
        acc[h] = MFMA(a1, b1, acc[h]);
        if (h < 11) {   // write next-h into other buffer (readers done)
            *(bf16x8*)&sT[s ^ 1][kdst] = rk;
            if (hasQ) *(bf16x8*)&sT[s ^ 1][qdst] = rq;
        }
    }

    // ---- epilogue: R1-verbatim mix + bias + store ------------------------
    int col = lane & 15, rb = (lane >> 4) * 4;
    #pragma unroll
    for (int g = 0; g < 12; ++g) {
        f32x4 s = fzero();
        #pragma unroll
        for (int h = 0; h < 12; ++h) {
            float w = wl[g * 12 + h];
            s += acc[h] * w;
        }
        #pragma unroll
        for (int r = 0; r < 4; ++r) {
            int n = n0 + rb + r;
            int m = m0 + col;
            float v = s[r] + (float)biasb[(size_t)(g * 256 + n) * 256 + m];
            S[((size_t)(b * 12 + g) * NP + n) * NP + m] = (__bf16)v;
        }
    }
}

// ---------------------------------------------------------------------------
// K34 fused: softmax (P in registers) + w_w post-mix + PV MFMA.
// (R14-green VT-staged version verbatim)
__global__ __launch_bounds__(512, 2) void k34_smx_pv(
    const __bf16* __restrict__ S, const __bf16* __restrict__ VT,
    const float* __restrict__ ww_, const float* __restrict__ bw_,
    __bf16* __restrict__ aout)
{
    __shared__ __attribute__((aligned(16))) __bf16 Pp[2][16][264];    // 16.9 KB
    __shared__ __attribute__((aligned(16))) __bf16 VTl[2 * 64 * 256]; // 64 KB
    __shared__ float ww[144];
    __shared__ float bw[12];
    int tid = threadIdx.x;
    if (tid < 144) ww[tid] = ww_[tid];
    if (tid >= 256 && tid < 268) bw[tid - 256] = bw_[tid - 256];

    // XCD swizzle: 16 same-b blocks -> same XCD
    int W = blockIdx.x;                 // 0..1023
    int g8 = W & 7, kk = W >> 3;
    int L = (kk >> 4) * 128 + g8 * 16 + (kk & 15);   // bijective
    int b = L >> 4, nt = L & 15;
    int n0 = nt * 16;

    int n = tid >> 5, ms = tid & 31;
    int lane = tid & 63, wave = tid >> 6;

    // ---- Phase A: per-(g,n)-row softmax; P kept in registers -------------
    float P[12][8];
    #pragma unroll
    for (int g = 0; g < 12; ++g) {
        const __bf16* rowp = S + ((size_t)(b * 12 + g) * NP + n0 + n) * NP + ms * 8;
        bf16x8 sv = *(const bf16x8*)rowp;
        float v[8];
        float mx = -1e30f;
        #pragma unroll
        for (int j = 0; j < 8; ++j) {
            v[j] = (ms * 8 + j < NN) ? (float)sv[j] : -1e30f;
            mx = fmaxf(mx, v[j]);
        }
        #pragma unroll
        for (int o = 16; o > 0; o >>= 1) mx = fmaxf(mx, __shfl_xor(mx, o));
        float sum = 0.f;
        #pragma unroll
        for (int j = 0; j < 8; ++j) {
            float e = (ms * 8 + j < NN) ? __expf(v[j] - mx) : 0.f;
            P[g][j] = e;
            sum += e;
        }
        #pragma unroll
        for (int o = 16; o > 0; o >>= 1) sum += __shfl_xor(sum, o);
        float inv = 1.f / sum;
        #pragma unroll
        for (int j = 0; j < 8; ++j) P[g][j] *= inv;
    }
    __syncthreads();   // also covers ww/bw loads

    // ---- Phase B: 6 chunks of {stage VT, mix 2 gp -> LDS, PV MFMA} -------
    int dt = wave >> 1, wgp = wave & 1;
    int lrow = lane & 15, lk = (lane >> 4) * 8, hh = lane >> 4;
    int col = lane & 15, rb = (lane >> 4) * 4;
    #pragma unroll 1
    for (int c = 0; c < 6; ++c) {
        // stage VT slices for gp = c*2+{0,1}: 4096 16B chunks, linear LDS
        // dest (wave-uniform+lane*16), source-swizzled within 128B spans.
        #pragma unroll
        for (int i = 0; i < 8; ++i) {
            int f = i * 512 + tid;            // 0..4095
            int wgs = f >> 11;                // which gp slice
            int cc = f & 2047;                // chunk within slice
            int row = cc >> 5, pc = cc & 31;
            int lch = pc ^ (row & 7);         // logical chunk at this slot
            const __bf16* src = VT + ((size_t)(b * 12 + c * 2 + wgs) * 64 + row) * NP + lch * 8;
            gl_lds16(src, VTl + (size_t)f * 8);
        }
        // w_w mix -> Pp (hides staging latency)
        #pragma unroll
        for (int gi = 0; gi < 2; ++gi) {
            int gp = c * 2 + gi;
            bf16x8 o;
            #pragma unroll
            for (int j = 0; j < 8; ++j) {
                float a = bw[gp];
                #pragma unroll
                for (int g = 0; g < 12; ++g) a += ww[gp * 12 + g] * P[g][j];
                o[j] = (__bf16)((ms * 8 + j < NN) ? a : 0.f);
            }
            *(bf16x8*)&Pp[gi][n][ms * 8] = o;
        }
        __syncthreads();   // Pp visible + vmcnt drained (VTl staged)
        f32x4 acc = fzero();
        const __bf16* vbase = VTl + (size_t)wgp * 16384 + (dt * 16 + lrow) * 256;
        #pragma unroll
        for (int kt = 0; kt < 8; ++kt) {
            bf16x8 av = *(const bf16x8*)&Pp[wgp][lrow][kt * 32 + lk];
            bf16x8 bv = *(const bf16x8*)(vbase + (((kt * 4 + hh) ^ (lrow & 7)) * 8));
            acc = MFMA(av, bv, acc);
        }
        int gp = c * 2 + wgp;
        #pragma unroll
        for (int r = 0; r < 4; ++r) {
            int gn = n0 + rb + r;
            if (gn < NN)
                aout[((size_t)b * NN + gn) * CC + gp * 64 + dt * 16 + col] = (__bf16)acc[r];
        }
        __syncthreads();   // Pp+VTl consumed; safe to overwrite next chunk
    }
}

// ---------------------------------------------------------------------------
extern "C" void kernel_launch(void* const* d_in, const int* in_sizes, int n_in,
                              void* d_out, int out_size, void* d_ws, size_t ws_size,
                              hipStream_t stream)
{
    (void)in_sizes; (void)n_in; (void)out_size; (void)ws_size;
    const float* x     = (const float*)d_in[0];
    const float* wqkv  = (const float*)d_in[1];
    const float* wproj = (const float*)d_in[2];
    const float* bproj = (const float*)d_in[3];
    const float* wl    = (const float*)d_in[4];
    const float* bl    = (const float*)d_in[5];
    const float* ww    = (const float*)d_in[6];
    const float* bw    = (const float*)d_in[7];
    const float* rpe   = (const float*)d_in[8];
    const int*   rel   = (const int*)d_in[9];

    char* ws = (char*)d_ws;
    const size_t SZ_QKV = (size_t)64 * 12 * 256 * 64 * 2;   // 25,165,824 B
    const size_t SZ_S   = (size_t)64 * 12 * 256 * 256 * 2;  // 100,663,296 B
    __bf16* Q     = (__bf16*)(ws);
    __bf16* Kb    = (__bf16*)(ws + SZ_QKV);
    __bf16* VT    = (__bf16*)(ws + 2 * SZ_QKV);
    __bf16* biasb = (__bf16*)(ws + 3 * SZ_QKV);              // 1.5 MB (bf16)
    char*   sreg  = ws + 3 * SZ_QKV + (size_t)12 * 256 * 256 * 4;
    __bf16* S     = (__bf16*)sreg;
    // xb/wb alias into the S region (dead before k2c writes S)
    __bf16* xb    = (__bf16*)sreg;                               // 24.1 MB
    __bf16* wb    = (__bf16*)(sreg + (size_t)MROWS * CC * 2);    //  3.5 MB
    __bf16* wpb   = (__bf16*)(ws + 3 * SZ_QKV + (size_t)12 * 256 * 256 * 4 + SZ_S);
    __bf16* aout  = Q;  // Q dead after k2c; reuse as attn-out

    // VT pad columns zeroed inside prep (blocks [3456,3648)) — no memset.
    prep<<<dim3(3648), 256, 0, stream>>>(x, xb, wqkv, wb, wproj, wpb,
                                         rpe, rel, wl, bl, biasb, VT);
    gemm128<0><<<dim3(18, 123), 256, 0, stream>>>(xb, wb, Q, Kb, VT, nullptr, nullptr);
    k2c_qk<<<dim3(2048), 512, 0, stream>>>(Q, Kb, biasb, wl, S);
    k34_smx_pv<<<dim3(1024), 512, 0, stream>>>(S, VT, ww, bw, aout);
    gemm128<1><<<dim3(6, 123), 256, 0, stream>>>(aout, wpb, nullptr, nullptr, nullptr,
                                                 bproj, (float*)d_out);
}

// Round 18
// 297.539 us; speedup vs baseline: 1.0277x; 1.0031x over previous
//
#include <hip/hip_runtime.h>
#include <hip/hip_bf16.h>

// Problem constants
#define NN 245      // tokens
#define NP 256      // padded tokens
#define HH 12       // heads
#define DD 64       // head dim
#define CC 768      // channels
#define NBUCKET 1698
#define MROWS (64 * NN)   // 15680

typedef __bf16 bf16x8 __attribute__((ext_vector_type(8)));
typedef float f32x4 __attribute__((ext_vector_type(4)));

#define MFMA(a, b, c) __builtin_amdgcn_mfma_f32_16x16x32_bf16(a, b, c, 0, 0, 0)

static __device__ __forceinline__ f32x4 fzero() {
    f32x4 z = {0.f, 0.f, 0.f, 0.f};
    return z;
}

static __device__ __forceinline__ bf16x8 cvt8(f32x4 lo, f32x4 hi) {
    bf16x8 r;
    #pragma unroll
    for (int i = 0; i < 4; ++i) { r[i] = (__bf16)lo[i]; r[i + 4] = (__bf16)hi[i]; }
    return r;
}

// async global->LDS, 16B per lane (wave-uniform LDS base + lane*16)
static __device__ __forceinline__ void gl_lds16(const __bf16* g, __bf16* l) {
    __builtin_amdgcn_global_load_lds(
        (const __attribute__((address_space(1))) void*)g,
        (__attribute__((address_space(3))) void*)l, 16, 0, 0);
}

// ---------------------------------------------------------------------------
// PREP (one launch, 3648 blocks of 256): 4 independent prep tasks concurrent
// + VT pad-column zeroing. (R10-green version verbatim)
__global__ __launch_bounds__(256) void prep(
    const float* __restrict__ x,     __bf16* __restrict__ xb,
    const float* __restrict__ wqkv,  __bf16* __restrict__ wb,
    const float* __restrict__ wproj, __bf16* __restrict__ wpb,
    const float* __restrict__ rpe, const int* __restrict__ relidx,
    const float* __restrict__ wl_, const float* __restrict__ bl_,
    __bf16* __restrict__ biasb, __bf16* __restrict__ VT)
{
    __shared__ float wl[144];
    __shared__ float bl[12];
    int bid = blockIdx.x, t = threadIdx.x;

    if (bid < 2048) {
        const int n8 = MROWS * CC / 8;
        int i = bid * 256 + t;
        int stride = 2048 * 256;
        for (; i < n8; i += stride) {
            f32x4 a = *(const f32x4*)(x + (size_t)i * 8);
            f32x4 b = *(const f32x4*)(x + (size_t)i * 8 + 4);
            *(bf16x8*)(xb + (size_t)i * 8) = cvt8(a, b);
        }
    } else if (bid < 2912) {
        int i = (bid - 2048) * 256 + t;          // 864*256 == 3*CC*CC/8 exact
        f32x4 a = *(const f32x4*)(wqkv + (size_t)i * 8);
        f32x4 b = *(const f32x4*)(wqkv + (size_t)i * 8 + 4);
        *(bf16x8*)(wb + (size_t)i * 8) = cvt8(a, b);
    } else if (bid < 3200) {
        int i = (bid - 2912) * 256 + t;          // 288*256 == CC*CC/8 exact
        f32x4 a = *(const f32x4*)(wproj + (size_t)i * 8);
        f32x4 b = *(const f32x4*)(wproj + (size_t)i * 8 + 4);
        *(bf16x8*)(wpb + (size_t)i * 8) = cvt8(a, b);
    } else if (bid < 3456) {
        // k0_bias verbatim (n = bid - 3200)
        if (t < 144) wl[t] = wl_[t];
        if (t < 12)  bl[t] = bl_[t];
        __syncthreads();
        int n = bid - 3200;   // 0..255
        int m = t;            // 0..255
        float r[12];
        bool valid = (n < NN) && (m < NN);
        if (valid) {
            int idx = relidx[n * NN + m];
            #pragma unroll
            for (int h = 0; h < 12; ++h) r[h] = rpe[h * NBUCKET + idx];
        }
        #pragma unroll
        for (int g = 0; g < 12; ++g) {
            float o = -30000.f;
            if (valid) {
                o = bl[g];
                #pragma unroll
                for (int h = 0; h < 12; ++h) o += wl[g * 12 + h] * r[h];
            }
            biasb[(size_t)(g * 256 + n) * 256 + m] = (__bf16)o;
        }
    } else {
        // VT pad zero: rows are (b*12+h)*64+d, 0..49151; cols [245,256)
        int row = (bid - 3456) * 256 + t;        // 192*256 == 49152 exact
        __bf16* p = VT + (size_t)row * NP + NN;
        __bf16 z = (__bf16)0.f;
        #pragma unroll
        for (int j = 0; j < 11; ++j) p[j] = z;
    }
}

// ---------------------------------------------------------------------------
// gemm128: m97-structure 128x128-tile NT GEMM (bf16 in, K=768, BK=32).
// R0-verified version verbatim (116.9 us green, 5x). GEMM family closed:
// dbuf, 256^2, BK=64+swizzle, counted-vmcnt (x2), and occupancy hint
// (R17: 3 blk/CU achieved but FETCH +18%, net neutral) all within
// 116-132 us — the 24-iteration barrier chain is the structural floor
// at this shape.
template<int EPI>
__global__ __launch_bounds__(256) void gemm128(
    const __bf16* __restrict__ A, const __bf16* __restrict__ Bw,
    __bf16* __restrict__ Q, __bf16* __restrict__ Kb, __bf16* __restrict__ VT,
    const float* __restrict__ bproj, float* __restrict__ outp)
{
    __shared__ __attribute__((aligned(16))) __bf16 sA[128 * 32];
    __shared__ __attribute__((aligned(16))) __bf16 sB[128 * 32];
    int tid = threadIdx.x, lane = tid & 63, wave = tid >> 6;

    // T1: XCD-chunked bijective swizzle
    int gx = gridDim.x;
    int nwg = gx * gridDim.y;
    int wg = blockIdx.y * gx + blockIdx.x;
    int q8 = nwg >> 3, r8 = nwg & 7;
    int xcd = wg & 7, idx = wg >> 3;
    int swz = (xcd < r8 ? xcd * (q8 + 1) : r8 * (q8 + 1) + (xcd - r8) * q8) + idx;
    int et = swz % gx, mt = swz / gx;
    int m0 = mt * 128, e0 = et * 128;

    int r1 = tid >> 2, chunk = tid & 3;
    int gar1 = m0 + r1;        if (gar1 >= MROWS) gar1 = MROWS - 1;
    int gar2 = m0 + 64 + r1;   if (gar2 >= MROWS) gar2 = MROWS - 1;
    const __bf16* aA1 = A  + (size_t)gar1 * CC + chunk * 8;
    const __bf16* aA2 = A  + (size_t)gar2 * CC + chunk * 8;
    const __bf16* aB1 = Bw + (size_t)(e0 + r1) * CC + chunk * 8;
    const __bf16* aB2 = Bw + (size_t)(e0 + 64 + r1) * CC + chunk * 8;
    __bf16* lA1 = sA + tid * 8;
    __bf16* lA2 = sA + tid * 8 + 2048;
    __bf16* lB1 = sB + tid * 8;
    __bf16* lB2 = sB + tid * 8 + 2048;

    int wr = wave >> 1, wc = wave & 1;
    int lrow = lane & 15, lk = (lane >> 4) * 8;
    const __bf16* ra = sA + (wr * 64 + lrow) * 32 + lk;
    const __bf16* rb = sB + (wc * 64 + lrow) * 32 + lk;

    f32x4 acc[4][4];
    #pragma unroll
    for (int q = 0; q < 4; ++q)
        #pragma unroll
        for (int n = 0; n < 4; ++n) acc[q][n] = fzero();

    for (int it = 0; it < 24; ++it) {
        __syncthreads();
        gl_lds16(aA1 + it * 32, lA1);
        gl_lds16(aA2 + it * 32, lA2);
        gl_lds16(aB1 + it * 32, lB1);
        gl_lds16(aB2 + it * 32, lB2);
        __syncthreads();
        bf16x8 af[4], bfr[4];
        #pragma unroll
        for (int q = 0; q < 4; ++q) af[q]  = *(const bf16x8*)(ra + q * 512);
        #pragma unroll
        for (int n = 0; n < 4; ++n) bfr[n] = *(const bf16x8*)(rb + n * 512);
        #pragma unroll
        for (int q = 0; q < 4; ++q)
            #pragma unroll
            for (int n = 0; n < 4; ++n)
                acc[q][n] = MFMA(af[q], bfr[n], acc[q][n]);
    }

    int col = lane & 15, rbs = (lane >> 4) * 4;
    #pragma unroll
    for (int q = 0; q < 4; ++q) {
        int gmb = m0 + wr * 64 + q * 16 + rbs;
        #pragma unroll
        for (int n = 0; n < 4; ++n) {
            int e = e0 + wc * 64 + n * 16 + col;
            if (EPI == 0) {
                int which = e / CC;
                int h = (e % CC) >> 6;
                int d = e & 63;
                #pragma unroll
                for (int r = 0; r < 4; ++r) {
                    int gm = gmb + r;
                    if (gm < MROWS) {
                        int bidx = gm / NN, nn = gm - bidx * NN;
                        float v = acc[q][n][r];
                        if (which == 0)
                            Q[((size_t)(bidx * 12 + h) * NP + nn) * 64 + d] = (__bf16)(v * 0.125f);
                        else if (which == 1)
                            Kb[((size_t)(bidx * 12 + h) * NP + nn) * 64 + d] = (__bf16)v;
                        else
                            VT[((size_t)(bidx * 12 + h) * 64 + d) * NP + nn] = (__bf16)v;
                    }
                }
            } else {
                float bv = bproj[e];
                #pragma unroll
                for (int r = 0; r < 4; ++r) {
                    int gm = gmb + r;
                    if (gm < MROWS)
                        outp[(size_t)gm * CC + e] = acc[q][n][r] + bv;
                }
            }
        }
    }
}

// ---------------------------------------------------------------------------
// K2c: S[b][g][n][m] = sum_h w_l[g,h]*(q_h.k_h) + bias'[g][n][m]  (bf16)
// (R13/R14-green LDS-staged version verbatim: coalesced staging killed the
// 16-segment fragment-load transaction serialization; 115 -> ~66 us.
// k2c closed.)
__global__ __launch_bounds__(512, 4) void k2c_qk(
    const __bf16* __restrict__ Q, const __bf16* __restrict__ Kb,
    const __bf16* __restrict__ biasb, const float* __restrict__ wl_,
    __bf16* __restrict__ S)
{
    // 96 rows (0-31: Q tile, 32-95: K tile) x 64 els, stride 72 els (144B).
    __shared__ __attribute__((aligned(16))) __bf16 sT[2][96 * 72];   // 27.6 KB
    __shared__ float wl[144];
    int tid = threadIdx.x, wave = tid >> 6, lane = tid & 63;
    if (tid < 144) wl[tid] = wl_[tid];   // covered by first loop barrier

    // XCD swizzle: 2048 blocks, 8 consecutive b per XCD (32 blocks per b).
    int wg = blockIdx.x;
    int L = (wg & 7) * 256 + (wg >> 3);
    int b = L >> 5, rem = L & 31;
    int mq = rem & 3, nt = rem >> 2;          // mq 0..3, nt 0..7
    int wn = wave >> 2, wm = wave & 3;
    int n0b = nt * 32, m0b = mq * 64;
    int n0 = n0b + wn * 16;
    int m0 = m0b + wm * 16;

    bool hasQ = (tid < 256);
    int kc = hasQ ? (tid + 256) : (tid - 256);              // K chunk 0..511
    int qsrc = (n0b + (tid >> 3)) * 64 + (tid & 7) * 8;     // elements
    int qdst = (tid >> 3) * 72 + (tid & 7) * 8;
    int ksrc = (m0b + (kc >> 3)) * 64 + (kc & 7) * 8;
    int kdst = (32 + (kc >> 3)) * 72 + (kc & 7) * 8;

    int lrow = lane & 15, lk = (lane >> 4) * 8;
    int aR = (wn * 16 + lrow) * 72 + lk;          // Q fragment base (els)
    int bR = (32 + wm * 16 + lrow) * 72 + lk;     // K fragment base (els)

    f32x4 acc[12];
    #pragma unroll
    for (int h = 0; h < 12; ++h) acc[h] = fzero();

    // prologue: stage h=0 into buf 0
    size_t hb = (size_t)(b * 12) << 14;           // *(NP*64)
    bf16x8 rk = *(const bf16x8*)(Kb + hb + ksrc);
    bf16x8 rq;
    if (hasQ) rq = *(const bf16x8*)(Q + hb + qsrc);
    *(bf16x8*)&sT[0][kdst] = rk;
    if (hasQ) *(bf16x8*)&sT[0][qdst] = rq;

    #pragma unroll
    for (int h = 0; h < 12; ++h) {
        int s = h & 1;
        if (h < 11) {   // issue next-h global loads (regs only, no LDS touch)
            size_t hb2 = (size_t)(b * 12 + h + 1) << 14;
            rk = *(const bf16x8*)(Kb + hb2 + ksrc);
            if (hasQ) rq = *(const bf16x8*)(Q + hb2 + qsrc);
        }
        __syncthreads();   // buf s writes visible; all reads of buf s^1 done
        bf16x8 a0 = *(const bf16x8*)&sT[s][aR];
        bf16x8 a1 = *(const bf16x8*)&sT[s][aR + 32];
        bf16x8 b0 = *(const bf16x8*)&sT[s][bR];
        bf16x8 b1 = *(const bf16x8*)&sT[s][bR + 32];
        acc[h] = MFMA(a0, b0, acc[h]);
        acc[h] = MFMA(a1, b1, acc[h]);
        if (h < 11) {   // write next-h into other buffer (readers done)
            *(bf16x8*)&sT[s ^ 1][kdst] = rk;
            if (hasQ) *(bf16x8*)&sT[s ^ 1][qdst] = rq;
        }
    }

    // ---- epilogue: R1-verbatim mix + bias + store ------------------------
    int col = lane & 15, rb = (lane >> 4) * 4;
    #pragma unroll
    for (int g = 0; g < 12; ++g) {
        f32x4 s = fzero();
        #pragma unroll
        for (int h = 0; h < 12; ++h) {
            float w = wl[g * 12 + h];
            s += acc[h] * w;
        }
        #pragma unroll
        for (int r = 0; r < 4; ++r) {
            int n = n0 + rb + r;
            int m = m0 + col;
            float v = s[r] + (float)biasb[(size_t)(g * 256 + n) * 256 + m];
            S[((size_t)(b * 12 + g) * NP + n) * NP + m] = (__bf16)v;
        }
    }
}

// ---------------------------------------------------------------------------
// K34 fused: softmax (P in registers) + w_w post-mix + PV MFMA.
// (R14-green VT-staged version verbatim: VT slices staged via
// global_load_lds with source-side XOR swizzle within 128B spans; fragment
// ds_read_b128 2-way banked; staging hidden under the w_w mix. 78 -> ~64 us)
__global__ __launch_bounds__(512, 2) void k34_smx_pv(
    const __bf16* __restrict__ S, const __bf16* __restrict__ VT,
    const float* __restrict__ ww_, const float* __restrict__ bw_,
    __bf16* __restrict__ aout)
{
    __shared__ __attribute__((aligned(16))) __bf16 Pp[2][16][264];    // 16.9 KB
    __shared__ __attribute__((aligned(16))) __bf16 VTl[2 * 64 * 256]; // 64 KB
    __shared__ float ww[144];
    __shared__ float bw[12];
    int tid = threadIdx.x;
    if (tid < 144) ww[tid] = ww_[tid];
    if (tid >= 256 && tid < 268) bw[tid - 256] = bw_[tid - 256];

    // XCD swizzle: 16 same-b blocks -> same XCD
    int W = blockIdx.x;                 // 0..1023
    int g8 = W & 7, kk = W >> 3;
    int L = (kk >> 4) * 128 + g8 * 16 + (kk & 15);   // bijective
    int b = L >> 4, nt = L & 15;
    int n0 = nt * 16;

    int n = tid >> 5, ms = tid & 31;
    int lane = tid & 63, wave = tid >> 6;

    // ---- Phase A: per-(g,n)-row softmax; P kept in registers -------------
    float P[12][8];
    #pragma unroll
    for (int g = 0; g < 12; ++g) {
        const __bf16* rowp = S + ((size_t)(b * 12 + g) * NP + n0 + n) * NP + ms * 8;
        bf16x8 sv = *(const bf16x8*)rowp;
        float v[8];
        float mx = -1e30f;
        #pragma unroll
        for (int j = 0; j < 8; ++j) {
            v[j] = (ms * 8 + j < NN) ? (float)sv[j] : -1e30f;
            mx = fmaxf(mx, v[j]);
        }
        #pragma unroll
        for (int o = 16; o > 0; o >>= 1) mx = fmaxf(mx, __shfl_xor(mx, o));
        float sum = 0.f;
        #pragma unroll
        for (int j = 0; j < 8; ++j) {
            float e = (ms * 8 + j < NN) ? __expf(v[j] - mx) : 0.f;
            P[g][j] = e;
            sum += e;
        }
        #pragma unroll
        for (int o = 16; o > 0; o >>= 1) sum += __shfl_xor(sum, o);
        float inv = 1.f / sum;
        #pragma unroll
        for (int j = 0; j < 8; ++j) P[g][j] *= inv;
    }
    __syncthreads();   // also covers ww/bw loads

    // ---- Phase B: 6 chunks of {stage VT, mix 2 gp -> LDS, PV MFMA} -------
    int dt = wave >> 1, wgp = wave & 1;
    int lrow = lane & 15, lk = (lane >> 4) * 8, hh = lane >> 4;
    int col = lane & 15, rb = (lane >> 4) * 4;
    #pragma unroll 1
    for (int c = 0; c < 6; ++c) {
        // stage VT slices for gp = c*2+{0,1}: 4096 16B chunks, linear LDS
        // dest (wave-uniform+lane*16), source-swizzled within 128B spans.
        #pragma unroll
        for (int i = 0; i < 8; ++i) {
            int f = i * 512 + tid;            // 0..4095
            int wgs = f >> 11;                // which gp slice
            int cc = f & 2047;                // chunk within slice
            int row = cc >> 5, pc = cc & 31;
            int lch = pc ^ (row & 7);         // logical chunk at this slot
            const __bf16* src = VT + ((size_t)(b * 12 + c * 2 + wgs) * 64 + row) * NP + lch * 8;
            gl_lds16(src, VTl + (size_t)f * 8);
        }
        // w_w mix -> Pp (hides staging latency)
        #pragma unroll
        for (int gi = 0; gi < 2; ++gi) {
            int gp = c * 2 + gi;
            bf16x8 o;
            #pragma unroll
            for (int j = 0; j < 8; ++j) {
                float a = bw[gp];
                #pragma unroll
                for (int g = 0; g < 12; ++g) a += ww[gp * 12 + g] * P[g][j];
                o[j] = (__bf16)((ms * 8 + j < NN) ? a : 0.f);
            }
            *(bf16x8*)&Pp[gi][n][ms * 8] = o;
        }
        __syncthreads();   // Pp visible + vmcnt drained (VTl staged)
        f32x4 acc = fzero();
        const __bf16* vbase = VTl + (size_t)wgp * 16384 + (dt * 16 + lrow) * 256;
        #pragma unroll
        for (int kt = 0; kt < 8; ++kt) {
            bf16x8 av = *(const bf16x8*)&Pp[wgp][lrow][kt * 32 + lk];
            bf16x8 bv = *(const bf16x8*)(vbase + (((kt * 4 + hh) ^ (lrow & 7)) * 8));
            acc = MFMA(av, bv, acc);
        }
        int gp = c * 2 + wgp;
        #pragma unroll
        for (int r = 0; r < 4; ++r) {
            int gn = n0 + rb + r;
            if (gn < NN)
                aout[((size_t)b * NN + gn) * CC + gp * 64 + dt * 16 + col] = (__bf16)acc[r];
        }
        __syncthreads();   // Pp+VTl consumed; safe to overwrite next chunk
    }
}

// ---------------------------------------------------------------------------
extern "C" void kernel_launch(void* const* d_in, const int* in_sizes, int n_in,
                              void* d_out, int out_size, void* d_ws, size_t ws_size,
                              hipStream_t stream)
{
    (void)in_sizes; (void)n_in; (void)out_size; (void)ws_size;
    const float* x     = (const float*)d_in[0];
    const float* wqkv  = (const float*)d_in[1];
    const float* wproj = (const float*)d_in[2];
    const float* bproj = (const float*)d_in[3];
    const float* wl    = (const float*)d_in[4];
    const float* bl    = (const float*)d_in[5];
    const float* ww    = (const float*)d_in[6];
    const float* bw    = (const float*)d_in[7];
    const float* rpe   = (const float*)d_in[8];
    const int*   rel   = (const int*)d_in[9];

    char* ws = (char*)d_ws;
    const size_t SZ_QKV = (size_t)64 * 12 * 256 * 64 * 2;   // 25,165,824 B
    const size_t SZ_S   = (size_t)64 * 12 * 256 * 256 * 2;  // 100,663,296 B
    __bf16* Q     = (__bf16*)(ws);
    __bf16* Kb    = (__bf16*)(ws + SZ_QKV);
    __bf16* VT    = (__bf16*)(ws + 2 * SZ_QKV);
    __bf16* biasb = (__bf16*)(ws + 3 * SZ_QKV);              // 1.5 MB (bf16)
    char*   sreg  = ws + 3 * SZ_QKV + (size_t)12 * 256 * 256 * 4;
    __bf16* S     = (__bf16*)sreg;
    // xb/wb alias into the S region (dead before k2c writes S)
    __bf16* xb    = (__bf16*)sreg;                               // 24.1 MB
    __bf16* wb    = (__bf16*)(sreg + (size_t)MROWS * CC * 2);    //  3.5 MB
    __bf16* wpb   = (__bf16*)(ws + 3 * SZ_QKV + (size_t)12 * 256 * 256 * 4 + SZ_S);
    __bf16* aout  = Q;  // Q dead after k2c; reuse as attn-out

    // VT pad columns zeroed inside prep (blocks [3456,3648)) — no memset.
    prep<<<dim3(3648), 256, 0, stream>>>(x, xb, wqkv, wb, wproj, wpb,
                                         rpe, rel, wl, bl, biasb, VT);
    gemm128<0><<<dim3(18, 123), 256, 0, stream>>>(xb, wb, Q, Kb, VT, nullptr, nullptr);
    k2c_qk<<<dim3(2048), 512, 0, stream>>>(Q, Kb, biasb, wl, S);
    k34_smx_pv<<<dim3(1024), 512, 0, stream>>>(S, VT, ww, bw, aout);
    gemm128<1><<<dim3(6, 123), 256, 0, stream>>>(aout, wpb, nullptr, nullptr, nullptr,
                                                 bproj, (float*)d_out);
}